// Round 7
// baseline (64.318 us; speedup 1.0000x reference)
//
#include <hip/hip_runtime.h>
#include <stdint.h>

// y[m][n] = scales[n] * sum_k x[m][k]*W[n][k] + bias[n]
// M=128, K=4096, N=11008. x fp32; W int8-valued int32 [N][K]; out fp32.
//
// Round-7 structure (kill the K-split: full-K blocks, 2-deep pipeline):
//   pack_x: x fp32 -> bf16 in MFMA A-frag order into ws (1 MiB, L2-resident).
//   gemm4w: 172 blocks (ks=1), 4 waves, wave = FULL M (128) x 16 cols.
//           B read once through L3 (~176 MB, the binding resource).
//           2-deep prefetch: 4 LDS A-buffers (64 KiB) + 4 named B-reg bufs,
//           each phase issues exactly 8 vmem ops (4 A-DMA + 4 B-loads);
//           s_waitcnt vmcnt(16) waits precisely for the phase issued TWO
//           chunks earlier -> covers ~1000+ cy of L3 latency with only
//           4 waves/CU. Epilogue fused (scales, bias) -> no partials, no
//           reduce kernel, no extra dispatch.
//   NOTE: no spills tolerated -- scratch vmem ops would break the hand
//   counted vmcnt. launch_bounds(256,1) gives VGPR headroom (~130 used).

#define M_ROWS 128
#define K_DIM  4096
#define N_DIM  11008
#define CHUNKS 64                       // K chunks of 64
#define NT64   (N_DIM / 64)             // 172 block n-tiles
#define XP_BYTES (M_ROWS * K_DIM * 2)   // 1 MiB packed bf16 x

typedef __attribute__((ext_vector_type(8))) short bf16x8;
typedef __attribute__((ext_vector_type(4))) float f32x4;
typedef const unsigned __attribute__((address_space(1)))* gas1_t;
typedef unsigned __attribute__((address_space(3)))* las3_t;

__device__ __forceinline__ unsigned bf16_rn(float f) {
  unsigned u = __float_as_uint(f);
  return (u + 0x7FFFu + ((u >> 16) & 1u)) >> 16;   // round-to-nearest-even
}
// two exact int->f32, pack top halves into 2xbf16 (truncate = exact, |w|<=128)
__device__ __forceinline__ unsigned pk2(int a, int b) {
  unsigned lo = __float_as_uint((float)a), hi = __float_as_uint((float)b);
#if __has_builtin(__builtin_amdgcn_perm)
  return __builtin_amdgcn_perm(hi, lo, 0x07060302u);
#else
  return (hi & 0xFFFF0000u) | (lo >> 16);
#endif
}

__device__ __forceinline__ void gload_lds16(const void* g, void* lds) {
#if __has_builtin(__builtin_amdgcn_global_load_lds)
  // generic LDS pointer low 32 bits == LDS byte offset (validated r2-r6)
  __builtin_amdgcn_global_load_lds((gas1_t)g, (las3_t)(size_t)(unsigned)(size_t)lds,
                                   16, 0, 0);
#else
  *(uint4*)lds = *(const uint4*)g;  // synchronous fallback (correct)
#endif
}

// barrier only: buffer hand-off (no data consumed yet)
#define BAR()    asm volatile("s_barrier" ::: "memory")
// wait for all but the newest N vmem ops, then barrier (r6-validated pattern:
// per-wave waitcnt before barrier => at barrier exit every wave's DMAs done)
#define WBAR16() asm volatile("s_waitcnt vmcnt(16)\n\ts_barrier" ::: "memory")
#define WBAR8()  asm volatile("s_waitcnt vmcnt(8)\n\ts_barrier" ::: "memory")
#define WBAR0()  asm volatile("s_waitcnt vmcnt(0)\n\ts_barrier" ::: "memory")

// ---------------- pack x: fp32 -> bf16 in A-frag order ----------------
// Chunk kk = 16 KiB: 16B unit u = (mf*2 + s)*64 + lane
// frag (mf,s): lane l holds x[16*mf + (l&15)][kk*64 + s*32 + 8*(l>>4) + j]
__global__ __launch_bounds__(256) void pack_x_kernel(
    const float* __restrict__ x, unsigned short* __restrict__ xp) {
  int tid  = blockIdx.x * 256 + threadIdx.x;   // 65536 threads
  int lane = tid & 63;
  int h    = (tid >> 6) & 1;
  int mf   = (tid >> 7) & 7;
  int kk   = tid >> 10;
  int m     = mf * 16 + (lane & 15);
  int kbase = kk * 64 + h * 32 + ((lane >> 4) * 8);
  const float* src = x + (size_t)m * K_DIM + kbase;
  float4 f0 = *(const float4*)(src);
  float4 f1 = *(const float4*)(src + 4);
  float v[8] = {f0.x, f0.y, f0.z, f0.w, f1.x, f1.y, f1.z, f1.w};
  unsigned po[4];
#pragma unroll
  for (int i = 0; i < 4; ++i)
    po[i] = bf16_rn(v[2 * i]) | (bf16_rn(v[2 * i + 1]) << 16);
  *(uint4*)(xp + (size_t)tid * 8) = *(uint4*)po;
}

// ---------------- 4-wave GEMM: block BM=128 x BN=64, full K ----------------
struct BReg { uint4 v[4]; };   // one chunk of B per lane: 16 ints

__global__ __launch_bounds__(256, 1) void gemm4w_kernel(
    const unsigned short* __restrict__ xp,
    const int* __restrict__ wq,
    const float* __restrict__ scales,
    const float* __restrict__ bias,
    float* __restrict__ out) {
  __shared__ char As[4 * 16384];       // 4-deep A ring (2 chunks in flight)

  const int tid  = threadIdx.x;
  const int lane = tid & 63;
  const int w    = tid >> 6;           // wave 0..3 -> cols [16w, 16w+16)
  const int nt   = blockIdx.x;         // 0..171
  const size_t n0 = (size_t)nt * 64 + (size_t)w * 16;
  const int l15 = lane & 15, lh = lane >> 4;

  // A staging: block covers 16 KiB/chunk; thread stages 4x16B, lane-linear
  const char* agp = (const char*)xp + tid * 16;
  // B: row n0 + l15; ints at t*64 + s*32 + lh*8 .. +8
  const int* bptr = wq + (n0 + (size_t)l15) * K_DIM + lh * 8;

  f32x4 acc[8];
  {
    f32x4 z = {0.f, 0.f, 0.f, 0.f};
#pragma unroll
    for (int i = 0; i < 8; ++i) acc[i] = z;
  }

  auto STAGE = [&](int t, int bufOff) {
#pragma unroll
    for (int i = 0; i < 4; ++i)
      gload_lds16(agp + (size_t)t * 16384 + (size_t)i * 4096,
                  As + bufOff + tid * 16 + i * 4096);
  };
  auto LOADB = [&](int t, BReg& R) {
    const int* bp = bptr + t * 64;
    R.v[0] = *(const uint4*)(bp);
    R.v[1] = *(const uint4*)(bp + 4);
    R.v[2] = *(const uint4*)(bp + 32);
    R.v[3] = *(const uint4*)(bp + 36);
  };
  auto COMP = [&](const char* ab, BReg& R) {
    bf16x8 cv[2];
#pragma unroll
    for (int s = 0; s < 2; ++s) {
      union { unsigned u[4]; bf16x8 b; } c;
      c.u[0] = pk2((int)R.v[s * 2].x,     (int)R.v[s * 2].y);
      c.u[1] = pk2((int)R.v[s * 2].z,     (int)R.v[s * 2].w);
      c.u[2] = pk2((int)R.v[s * 2 + 1].x, (int)R.v[s * 2 + 1].y);
      c.u[3] = pk2((int)R.v[s * 2 + 1].z, (int)R.v[s * 2 + 1].w);
      cv[s] = c.b;
    }
#pragma unroll
    for (int mf = 0; mf < 8; ++mf)
#pragma unroll
      for (int s = 0; s < 2; ++s) {
        bf16x8 a = *(const bf16x8*)(ab + (mf * 2 + s) * 1024 + lane * 16);
        acc[mf] = __builtin_amdgcn_mfma_f32_16x16x32_bf16(a, cv[s], acc[mf], 0, 0, 0);
      }
  };

  // Steady-state invariant: 24 vmem ops outstanding before each WBAR16;
  // vmcnt(16) drains exactly phase-t's 8 (A-DMA t, B t), issued 2 chunks ago.
#define PHASE(T, RCUR, RNXT)                       \
    LOADB((T) + 2, RNXT);                          \
    BAR();                                         \
    STAGE((T) + 2, (((T) + 2) & 3) * 16384);       \
    WBAR16();                                      \
    COMP(As + ((T) & 3) * 16384, RCUR);

  BReg R0, R1, R2, R3;
  // prologue: chunks 0,1 in flight (16 ops)
  STAGE(0, 0);
  LOADB(0, R0);
  STAGE(1, 16384);
  LOADB(1, R1);

#pragma unroll 1
  for (int t = 0; t < CHUNKS - 4; t += 4) {        // t = 0..56, phases 0..59
    PHASE(t + 0, R0, R2);
    PHASE(t + 1, R1, R3);
    PHASE(t + 2, R2, R0);
    PHASE(t + 3, R3, R1);
  }
  PHASE(CHUNKS - 4, R0, R2);                       // phase 60, issues 62
  PHASE(CHUNKS - 3, R1, R3);                       // phase 61, issues 63
  WBAR8();                                         // phase 62 resident
  COMP(As + 2 * 16384, R2);
  WBAR0();                                         // phase 63 resident
  COMP(As + 3 * 16384, R3);
#undef PHASE

  // fused epilogue: m = mf*16 + lh*4 + r ; n = n0 + l15
  const size_t n = n0 + (size_t)l15;
  const float sc = scales[n], bi = bias[n];
#pragma unroll
  for (int mf = 0; mf < 8; ++mf) {
    const int mb = mf * 16 + lh * 4;
#pragma unroll
    for (int r = 0; r < 4; ++r)
      out[(size_t)(mb + r) * N_DIM + n] = sc * acc[mf][r] + bi;
  }
}

// ---------------- insurance path if ws is tiny ----------------
__global__ __launch_bounds__(256) void naive_kernel(
    const float* __restrict__ x, const int* __restrict__ wq,
    const float* __restrict__ scales, const float* __restrict__ bias,
    float* __restrict__ out) {
  const int n = blockIdx.x * 256 + threadIdx.x;
  const int m = blockIdx.y;
  const float* xr = x + (size_t)m * K_DIM;
  const int* wr = wq + (size_t)n * K_DIM;
  float s = 0.f;
  for (int k = 0; k < K_DIM; k += 4) {
    float4 xv = *(const float4*)(xr + k);
    int4  wv = *(const int4*)(wr + k);
    s += xv.x * (float)wv.x + xv.y * (float)wv.y +
         xv.z * (float)wv.z + xv.w * (float)wv.w;
  }
  out[(size_t)m * N_DIM + n] = scales[n] * s + bias[n];
}

extern "C" void kernel_launch(void* const* d_in, const int* in_sizes, int n_in,
                              void* d_out, int out_size, void* d_ws, size_t ws_size,
                              hipStream_t stream) {
  const float* x      = (const float*)d_in[0];
  const int* wq       = (const int*)d_in[1];
  const float* scales = (const float*)d_in[2];
  const float* bias   = (const float*)d_in[3];
  float* out          = (float*)d_out;

  if (ws_size < (size_t)XP_BYTES) {
    naive_kernel<<<dim3(N_DIM / 256, M_ROWS), 256, 0, stream>>>(x, wq, scales, bias, out);
    return;
  }
  unsigned short* xp = (unsigned short*)d_ws;

  pack_x_kernel<<<256, 256, 0, stream>>>(x, xp);
  gemm4w_kernel<<<dim3(NT64), 256, 0, stream>>>(xp, wq, scales, bias, out);
}

// Round 8
// 52.548 us; speedup vs baseline: 1.2240x; 1.2240x over previous
//
#include <hip/hip_runtime.h>
#include <stdint.h>

// y[m][n] = scales[n] * sum_k x[m][k]*W[n][k] + bias[n]
// M=128, K=4096, N=11008. x fp32; W int8-valued int32 [N][K]; out fp32.
//
// Round-8 structure (r6 grid + r7 pipeline depth):
//   pack_x: x fp32 -> bf16 in MFMA A-frag order into ws (1 MiB, L2-resident).
//   gemm4w: ks=4 -> 688 blocks (all 256 CUs covered, r7 lesson), 4 waves,
//           wave = FULL M (128) x 16 cols, block BN=64, cpb=16 chunks.
//           2-deep prefetch: 3-buffer LDS ring (48 KiB -> 3 blocks/CU
//           resident = 12 waves/CU) + 3 rotating named B-reg buffers.
//           Each phase issues exactly 8 vmem ops (4 A-DMA + 4 B-loads);
//           vmcnt(16) waits for the phase issued TWO chunks earlier.
//           In-flight/CU ~192 ops vs r6's ~85 (the 18 GB/s/CU limiter).
//   reduce: out = scales*(sum of 4 partials) + bias (deterministic).
//   NOTE: no spills tolerated (scratch ops would break hand-counted vmcnt);
//   launch_bounds(256,3) -> VGPR cap 168, est. use ~130.

#define M_ROWS 128
#define K_DIM  4096
#define N_DIM  11008
#define CHUNKS 64                       // K chunks of 64
#define NT64   (N_DIM / 64)             // 172 block n-tiles
#define KSPLIT 4
#define CPB    (CHUNKS / KSPLIT)        // 16 chunks per block
#define XP_BYTES (M_ROWS * K_DIM * 2)   // 1 MiB packed bf16 x
#define PART_ELEMS ((size_t)M_ROWS * (size_t)N_DIM)

typedef __attribute__((ext_vector_type(8))) short bf16x8;
typedef __attribute__((ext_vector_type(4))) float f32x4;
typedef const unsigned __attribute__((address_space(1)))* gas1_t;
typedef unsigned __attribute__((address_space(3)))* las3_t;

__device__ __forceinline__ unsigned bf16_rn(float f) {
  unsigned u = __float_as_uint(f);
  return (u + 0x7FFFu + ((u >> 16) & 1u)) >> 16;   // round-to-nearest-even
}
// two exact int->f32, pack top halves into 2xbf16 (truncate = exact, |w|<=128)
__device__ __forceinline__ unsigned pk2(int a, int b) {
  unsigned lo = __float_as_uint((float)a), hi = __float_as_uint((float)b);
#if __has_builtin(__builtin_amdgcn_perm)
  return __builtin_amdgcn_perm(hi, lo, 0x07060302u);
#else
  return (hi & 0xFFFF0000u) | (lo >> 16);
#endif
}

__device__ __forceinline__ void gload_lds16(const void* g, void* lds) {
#if __has_builtin(__builtin_amdgcn_global_load_lds)
  // generic LDS pointer low 32 bits == LDS byte offset (validated r2-r7)
  __builtin_amdgcn_global_load_lds((gas1_t)g, (las3_t)(size_t)(unsigned)(size_t)lds,
                                   16, 0, 0);
#else
  *(uint4*)lds = *(const uint4*)g;  // synchronous fallback (correct)
#endif
}

// barrier only: LDS buffer hand-off (no new data consumed)
#define BAR()    asm volatile("s_barrier" ::: "memory")
// wait for all but the newest N vmem ops, then barrier. Per-wave waitcnt
// before s_barrier => at barrier exit, every wave's counted DMAs are done.
#define WBAR16() asm volatile("s_waitcnt vmcnt(16)\n\ts_barrier" ::: "memory")
#define WBAR8()  asm volatile("s_waitcnt vmcnt(8)\n\ts_barrier" ::: "memory")
#define WBAR0()  asm volatile("s_waitcnt vmcnt(0)\n\ts_barrier" ::: "memory")

// ---------------- pack x: fp32 -> bf16 in A-frag order ----------------
// Chunk kk = 16 KiB: 16B unit u = (mf*2 + s)*64 + lane
// frag (mf,s): lane l holds x[16*mf + (l&15)][kk*64 + s*32 + 8*(l>>4) + j]
__global__ __launch_bounds__(256) void pack_x_kernel(
    const float* __restrict__ x, unsigned short* __restrict__ xp) {
  int tid  = blockIdx.x * 256 + threadIdx.x;   // 65536 threads
  int lane = tid & 63;
  int h    = (tid >> 6) & 1;
  int mf   = (tid >> 7) & 7;
  int kk   = tid >> 10;
  int m     = mf * 16 + (lane & 15);
  int kbase = kk * 64 + h * 32 + ((lane >> 4) * 8);
  const float* src = x + (size_t)m * K_DIM + kbase;
  float4 f0 = *(const float4*)(src);
  float4 f1 = *(const float4*)(src + 4);
  float v[8] = {f0.x, f0.y, f0.z, f0.w, f1.x, f1.y, f1.z, f1.w};
  unsigned po[4];
#pragma unroll
  for (int i = 0; i < 4; ++i)
    po[i] = bf16_rn(v[2 * i]) | (bf16_rn(v[2 * i + 1]) << 16);
  *(uint4*)(xp + (size_t)tid * 8) = *(uint4*)po;
}

// ---------------- 4-wave GEMM: block BM=128 x BN=64, cpb=16 chunks ---------
struct BReg { uint4 v[4]; };   // one chunk of B per lane: 16 ints

__global__ __launch_bounds__(256, 3) void gemm4w_kernel(
    const unsigned short* __restrict__ xp,
    const int* __restrict__ wq,
    float* __restrict__ part) {
  __shared__ char As[3 * 16384];       // 3-buffer ring (2 chunks in flight)

  const int tid  = threadIdx.x;
  const int lane = tid & 63;
  const int w    = tid >> 6;           // wave 0..3 -> cols [16w, 16w+16)
  const int nt   = blockIdx.x;         // 0..171
  const int kz   = blockIdx.y;         // 0..3
  const int kk0  = kz * CPB;
  const size_t n0 = (size_t)nt * 64 + (size_t)w * 16;
  const int l15 = lane & 15, lh = lane >> 4;

  // A staging: block covers 16 KiB/chunk; thread stages 4x16B, lane-linear
  const char* agp = (const char*)xp + (size_t)kk0 * 16384 + tid * 16;
  // B: row n0 + l15; ints at (kk0+t)*64 + s*32 + lh*8 .. +8
  const int* bptr = wq + (n0 + (size_t)l15) * K_DIM + (size_t)kk0 * 64 + lh * 8;

  f32x4 acc[8];
  {
    f32x4 z = {0.f, 0.f, 0.f, 0.f};
#pragma unroll
    for (int i = 0; i < 8; ++i) acc[i] = z;
  }

  auto STAGE = [&](int t, int bufOff) {
#pragma unroll
    for (int i = 0; i < 4; ++i)
      gload_lds16(agp + (size_t)t * 16384 + (size_t)i * 4096,
                  As + bufOff + tid * 16 + i * 4096);
  };
  auto LOADB = [&](int t, BReg& R) {
    const int* bp = bptr + t * 64;
    R.v[0] = *(const uint4*)(bp);
    R.v[1] = *(const uint4*)(bp + 4);
    R.v[2] = *(const uint4*)(bp + 32);
    R.v[3] = *(const uint4*)(bp + 36);
  };
  auto COMP = [&](const char* ab, BReg& R) {
    bf16x8 cv[2];
#pragma unroll
    for (int s = 0; s < 2; ++s) {
      union { unsigned u[4]; bf16x8 b; } c;
      c.u[0] = pk2((int)R.v[s * 2].x,     (int)R.v[s * 2].y);
      c.u[1] = pk2((int)R.v[s * 2].z,     (int)R.v[s * 2].w);
      c.u[2] = pk2((int)R.v[s * 2 + 1].x, (int)R.v[s * 2 + 1].y);
      c.u[3] = pk2((int)R.v[s * 2 + 1].z, (int)R.v[s * 2 + 1].w);
      cv[s] = c.b;
    }
#pragma unroll
    for (int mf = 0; mf < 8; ++mf)
#pragma unroll
      for (int s = 0; s < 2; ++s) {
        bf16x8 a = *(const bf16x8*)(ab + (mf * 2 + s) * 1024 + lane * 16);
        acc[mf] = __builtin_amdgcn_mfma_f32_16x16x32_bf16(a, cv[s], acc[mf], 0, 0, 0);
      }
  };

  // phase T: consume chunk T from ring buf T%3 / reg R[T%3];
  // issue chunk T+2 into ring (T+2)%3 / reg R[(T+2)%3] (freed at phase T-1).
  // Outstanding before WBAR16: chunks T, T+1, T+2 = 24 ops -> drains T's 8.
#define PHASE(T, CBUF, NBUF, RC, RN)              \
    LOADB((T) + 2, RN);                           \
    BAR();                                        \
    STAGE((T) + 2, (NBUF) * 16384);               \
    WBAR16();                                     \
    COMP(As + (CBUF) * 16384, RC);

  BReg R0, R1, R2;
  // prologue: chunks 0,1 in flight (16 ops)
  STAGE(0, 0);
  LOADB(0, R0);
  STAGE(1, 16384);
  LOADB(1, R1);

#pragma unroll 1
  for (int t = 0; t < 12; t += 3) {      // phases 0..11 (issue chunks 2..13)
    PHASE(t + 0, 0, 2, R0, R2);
    PHASE(t + 1, 1, 0, R1, R0);
    PHASE(t + 2, 2, 1, R2, R1);
  }
  PHASE(12, 0, 2, R0, R2);               // issues chunk 14
  PHASE(13, 1, 0, R1, R0);               // issues chunk 15
  WBAR8();                               // chunk 14 resident (buf2, R2)
  COMP(As + 2 * 16384, R2);
  WBAR0();                               // chunk 15 resident (buf0, R0)
  COMP(As + 0 * 16384, R0);
#undef PHASE

  // partial-sum epilogue: m = mf*16 + lh*4 + r ; n = n0 + l15
  float* pb = part + (size_t)kz * PART_ELEMS + n0 + l15;
#pragma unroll
  for (int mf = 0; mf < 8; ++mf) {
    const int mb = mf * 16 + lh * 4;
#pragma unroll
    for (int r = 0; r < 4; ++r)
      pb[(size_t)(mb + r) * N_DIM] = acc[mf][r];
  }
}

// ---------------- combine partials + epilogue ----------------
__global__ __launch_bounds__(256) void reduce_kernel(
    const float* __restrict__ part, const float* __restrict__ scales,
    const float* __restrict__ bias, float* __restrict__ out) {
  const int m = blockIdx.y;
  const int c4 = blockIdx.x * 256 + threadIdx.x;
  if (c4 >= N_DIM / 4) return;
  const size_t n = (size_t)c4 * 4;
  const float* p = part + (size_t)m * N_DIM + n;
  float4 s = *(const float4*)(p);
#pragma unroll
  for (int z = 1; z < KSPLIT; ++z) {
    float4 q = *(const float4*)(p + (size_t)z * PART_ELEMS);
    s.x += q.x; s.y += q.y; s.z += q.z; s.w += q.w;
  }
  float4 sc = *(const float4*)(scales + n);
  float4 bi = *(const float4*)(bias + n);
  float4 r;
  r.x = sc.x * s.x + bi.x;
  r.y = sc.y * s.y + bi.y;
  r.z = sc.z * s.z + bi.z;
  r.w = sc.w * s.w + bi.w;
  *(float4*)(out + (size_t)m * N_DIM + n) = r;
}

// ---------------- insurance path if ws is tiny ----------------
__global__ __launch_bounds__(256) void naive_kernel(
    const float* __restrict__ x, const int* __restrict__ wq,
    const float* __restrict__ scales, const float* __restrict__ bias,
    float* __restrict__ out) {
  const int n = blockIdx.x * 256 + threadIdx.x;
  const int m = blockIdx.y;
  const float* xr = x + (size_t)m * K_DIM;
  const int* wr = wq + (size_t)n * K_DIM;
  float s = 0.f;
  for (int k = 0; k < K_DIM; k += 4) {
    float4 xv = *(const float4*)(xr + k);
    int4  wv = *(const int4*)(wr + k);
    s += xv.x * (float)wv.x + xv.y * (float)wv.y +
         xv.z * (float)wv.z + xv.w * (float)wv.w;
  }
  out[(size_t)m * N_DIM + n] = scales[n] * s + bias[n];
}

extern "C" void kernel_launch(void* const* d_in, const int* in_sizes, int n_in,
                              void* d_out, int out_size, void* d_ws, size_t ws_size,
                              hipStream_t stream) {
  const float* x      = (const float*)d_in[0];
  const int* wq       = (const int*)d_in[1];
  const float* scales = (const float*)d_in[2];
  const float* bias   = (const float*)d_in[3];
  float* out          = (float*)d_out;

  const size_t need = (size_t)XP_BYTES + KSPLIT * PART_ELEMS * sizeof(float);
  if (ws_size < need) {
    naive_kernel<<<dim3(N_DIM / 256, M_ROWS), 256, 0, stream>>>(x, wq, scales, bias, out);
    return;
  }
  unsigned short* xp = (unsigned short*)d_ws;
  float* part        = (float*)((char*)d_ws + XP_BYTES);

  pack_x_kernel<<<256, 256, 0, stream>>>(x, xp);
  gemm4w_kernel<<<dim3(NT64, KSPLIT), 256, 0, stream>>>(xp, wq, part);
  reduce_kernel<<<dim3((N_DIM / 4 + 255) / 256, M_ROWS), 256, 0, stream>>>(
      part, scales, bias, out);
}